// Round 8
// baseline (288.446 us; speedup 1.0000x reference)
//
#include <hip/hip_runtime.h>
#include <cstdint>
#include <cstddef>

#define N_TOK 32768
#define DIM   1024
#define NE    64
#define RPB   64
#define CH    64
#define NCH   (DIM / CH)          // 16
#define PITCH 68                  // floats per LDS row (64 + 4 pad) -> 17 16B slots
#define XFLTS (RPB * PITCH)       // 4352 floats = 17408 B per buffer
#define NSLICE 17                 // 17408 / 1024 DMA slices per buffer

// global -> LDS direct DMA, 16B per lane; LDS dest = wave-uniform base + lane*16
__device__ __forceinline__ void gload16(const float* g, float* l) {
  __builtin_amdgcn_global_load_lds(
      (const __attribute__((address_space(1))) uint32_t*)g,
      (__attribute__((address_space(3))) uint32_t*)l, 16, 0, 0);
}

// arg2 = min BLOCKS/CU on this toolchain (r4/r5 verified): 2 -> 128-VGPR cap.
__global__ __launch_bounds__(512, 2) void router_kernel(
    const float* __restrict__ x, const float* __restrict__ W,
    const float* __restrict__ bias, float* __restrict__ probs,
    float* __restrict__ idxo) {
  // 34.8 KB LDS: xs[2][64 rows][68 floats] (padded pitch: bank-conflict-free,
  // row stride 17 dwords coprime with 32 banks). Epilogue logits reuse buf 0.
  __shared__ __align__(1024) float xs[2 * XFLTS];

  const int tid  = threadIdx.x;
  const int lane = tid & 63;
  const int w    = __builtin_amdgcn_readfirstlane(tid >> 6);  // 0..7
  const int e0   = w * 8;          // this wave's 8 experts
  const int r0   = blockIdx.x * RPB;

  // ---- DMA slice setup: 17 x 1KB slices per buffer.
  // wave w stages slices 2w, 2w+1; wave 0 also slice 16.
  // slice j, lane l covers buffer bytes [j*1024 + 16l, +16):
  //   row = off/272, rem = off%272; rem>=256 is the pad slot (content unused).
  // 272 = 17*16, so every 16B slot lies wholly inside one row.
  // Source is per-lane (pre-swizzled for the padded layout), dest is linear.
  const float* srcs[3];
  int dstoff[3];
  const int nsl = (w == 0) ? 3 : 2;
  {
    const int js[3] = {2 * w, 2 * w + 1, 16};
#pragma unroll
    for (int s = 0; s < 3; ++s) {
      const int off = js[s] * 1024 + lane * 16;
      const int row = off / 272;
      const int rem = off % 272;
      const int col = (rem >= 256) ? 0 : (rem >> 2);  // pad -> col 0 (in-bounds dummy)
      srcs[s]   = x + (size_t)(r0 + row) * DIM + col;
      dstoff[s] = js[s] * 256;                        // float offset in buffer
    }
  }
  auto stage = [&](int buf) {
    float* base = xs + buf * XFLTS;
#pragma unroll
    for (int s = 0; s < 3; ++s) {
      if (s < nsl) {                 // wave-uniform predicate
        gload16(srcs[s], base + dstoff[s]);
        srcs[s] += CH;               // next chunk's k-window
      }
    }
  };

  float acc[8];
#pragma unroll
  for (int e = 0; e < 8; ++e) acc[e] = 0.0f;

  stage(0);

  for (int cc = 0; cc < NCH; ++cc) {
    __syncthreads();                 // chunk cc staged; buffers protected
    if (cc + 1 < NCH) stage((cc + 1) & 1);

    const float* xb = xs + (cc & 1) * XFLTS + lane * PITCH;  // this lane's row
    const float* Wc = W + (size_t)(cc * CH) * NE + e0;       // wave-uniform -> SGPR

#pragma unroll
    for (int g = 0; g < 8; ++g) {    // 8 kk per group: 2 ds_read_b128 + 64 reg FMA
      const float4 xq0 = *(const float4*)(xb + g * 8);
      const float4 xq1 = *(const float4*)(xb + g * 8 + 4);
#define KKSTEP(KK, XS)                                              \
      { const float4 wa = *(const float4*)(Wc + (g * 8 + KK) * NE); \
        const float4 wb = *(const float4*)(Wc + (g * 8 + KK) * NE + 4); \
        acc[0] = fmaf(XS, wa.x, acc[0]); acc[1] = fmaf(XS, wa.y, acc[1]); \
        acc[2] = fmaf(XS, wa.z, acc[2]); acc[3] = fmaf(XS, wa.w, acc[3]); \
        acc[4] = fmaf(XS, wb.x, acc[4]); acc[5] = fmaf(XS, wb.y, acc[5]); \
        acc[6] = fmaf(XS, wb.z, acc[6]); acc[7] = fmaf(XS, wb.w, acc[7]); }
      KKSTEP(0, xq0.x) KKSTEP(1, xq0.y) KKSTEP(2, xq0.z) KKSTEP(3, xq0.w)
      KKSTEP(4, xq1.x) KKSTEP(5, xq1.y) KKSTEP(6, xq1.z) KKSTEP(7, xq1.w)
#undef KKSTEP
    }
  }

  // ---- epilogue: logits tile (row-major, pitch 68) in buf 0 ----
  // Safe without a barrier: writers touch buf0; any straggler still computing
  // chunk 15 reads buf1 (disjoint).
  {
    const float4 b03 = *(const float4*)(bias + e0);
    const float4 b47 = *(const float4*)(bias + e0 + 4);
    float* lg = xs + lane * PITCH + e0;
    *(float4*)(lg)     = make_float4(acc[0] + b03.x, acc[1] + b03.y,
                                     acc[2] + b03.z, acc[3] + b03.w);
    *(float4*)(lg + 4) = make_float4(acc[4] + b47.x, acc[5] + b47.y,
                                     acc[6] + b47.z, acc[7] + b47.w);
  }
  __syncthreads();

  // per-row top2: wave w owns rows 8w..8w+7; lane -> (row, expert-oct)
  {
    const int row = w * 8 + (lane >> 3);
    const int oct = lane & 7;
    const float* lr = xs + row * PITCH + oct * 8;
    const float4 A = *(const float4*)(lr);
    const float4 B = *(const float4*)(lr + 4);
    const float av[8] = {A.x, A.y, A.z, A.w, B.x, B.y, B.z, B.w};

    float v1, v2, j1, j2;
    if (av[1] > av[0]) { v1 = av[1]; j1 = (float)(oct*8+1); v2 = av[0]; j2 = (float)(oct*8+0); }
    else               { v1 = av[0]; j1 = (float)(oct*8+0); v2 = av[1]; j2 = (float)(oct*8+1); }
#pragma unroll
    for (int e = 2; e < 8; ++e) {
      const float a = av[e]; const float jf = (float)(oct*8+e);
      if (a > v1)      { v2 = v1; j2 = j1; v1 = a; j1 = jf; }
      else if (a > v2) { v2 = a; j2 = jf; }
    }
#pragma unroll
    for (int m = 1; m <= 4; m <<= 1) {   // merge the 8 oct-lanes of this row
      const float u1  = __shfl_xor(v1, m, 64);
      const float uj1 = __shfl_xor(j1, m, 64);
      const float u2  = __shfl_xor(v2, m, 64);
      const float uj2 = __shfl_xor(j2, m, 64);
      const bool uwin = (u1 > v1) || (u1 == v1 && uj1 < j1);
      const float t1 = uwin ? u1 : v1,  tj1 = uwin ? uj1 : j1;
      const float l1 = uwin ? v1 : u1,  lj1 = uwin ? j1 : uj1;
      const float c2 = uwin ? u2 : v2,  cj2 = uwin ? uj2 : j2;
      const bool sw = (c2 > l1) || (c2 == l1 && cj2 < lj1);
      v1 = t1; j1 = tj1;
      v2 = sw ? c2 : l1; j2 = sw ? cj2 : lj1;
    }
    const float ex = __expf(v2 - v1);
    const float p1 = 1.0f / (1.0f + ex);
    const float p2 = ex * p1;
    const int ij1 = (int)j1, ij2 = (int)j2;
    float* op = probs + (size_t)(r0 + row) * NE + oct * 8;
    float4 o0, o1;
    const int eb = oct * 8;
    o0.x = (eb+0 == ij1) ? p1 : (eb+0 == ij2) ? p2 : 0.0f;
    o0.y = (eb+1 == ij1) ? p1 : (eb+1 == ij2) ? p2 : 0.0f;
    o0.z = (eb+2 == ij1) ? p1 : (eb+2 == ij2) ? p2 : 0.0f;
    o0.w = (eb+3 == ij1) ? p1 : (eb+3 == ij2) ? p2 : 0.0f;
    o1.x = (eb+4 == ij1) ? p1 : (eb+4 == ij2) ? p2 : 0.0f;
    o1.y = (eb+5 == ij1) ? p1 : (eb+5 == ij2) ? p2 : 0.0f;
    o1.z = (eb+6 == ij1) ? p1 : (eb+6 == ij2) ? p2 : 0.0f;
    o1.w = (eb+7 == ij1) ? p1 : (eb+7 == ij2) ? p2 : 0.0f;
    *(float4*)(op)     = o0;
    *(float4*)(op + 4) = o1;
    if (oct == 0) {
      float2 oi; oi.x = j1; oi.y = j2;
      *(float2*)(idxo + (size_t)(r0 + row) * 2) = oi;
    }
  }
}

extern "C" void kernel_launch(void* const* d_in, const int* in_sizes, int n_in,
                              void* d_out, int out_size, void* d_ws, size_t ws_size,
                              hipStream_t stream) {
  (void)in_sizes; (void)n_in; (void)out_size; (void)d_ws; (void)ws_size;
  const float* x = (const float*)d_in[0];
  const float* W = (const float*)d_in[1];
  const float* b = (const float*)d_in[2];
  float* out  = (float*)d_out;
  float* idxo = out + (size_t)N_TOK * NE;   // indices chunk follows probs chunk

  dim3 grid(N_TOK / RPB);   // 512 blocks
  dim3 block(512);
  hipLaunchKernelGGL(router_kernel, grid, block, 0, stream, x, W, b, out, idxo);
}